// Round 4
// baseline (1147.726 us; speedup 1.0000x reference)
//
#include <hip/hip_runtime.h>
#include <hip/hip_bf16.h>
#include <math.h>

#define B_ 512
#define D_ 256
#define NH_ 4
#define NN_ 512
#define NTOT_ 2048
#define DH_ 64
#define KSTEPS 8
#define NBLK 256u

typedef __attribute__((ext_vector_type(8))) short bf16x8;
typedef __attribute__((ext_vector_type(4))) float f32x4;

#if __has_builtin(__builtin_amdgcn_global_load_lds)
#define HAVE_GLL 1
#else
#define HAVE_GLL 0
#endif

__device__ __forceinline__ float gelu_exact(float x) {
  return 0.5f * x * (1.0f + erff(x * 0.70710678118654752f));
}

__device__ __forceinline__ unsigned short f2b(float f) {
  union { float f; unsigned int u; } x; x.f = f;
  unsigned int u = x.u;
  unsigned int r = (u + 0x7FFFu + ((u >> 16) & 1u)) >> 16;
  return (unsigned short)r;
}

#if HAVE_GLL
__device__ __forceinline__ void load16_lds(const unsigned short* g, unsigned short* l) {
  __builtin_amdgcn_global_load_lds(
      (const __attribute__((address_space(1))) unsigned int*)g,
      (__attribute__((address_space(3))) unsigned int*)l, 16, 0, 0);
}
#endif

// ---- device-wide barrier: monotonic counter, no reset race ----
__device__ __forceinline__ void gridbar(unsigned* bar, unsigned bi) {
  __syncthreads();
  if (threadIdx.x == 0) {
    __threadfence();
    atomicAdd(bar, 1u);
    const unsigned target = (bi + 1u) * NBLK;
    while (__hip_atomic_load(bar, __ATOMIC_RELAXED, __HIP_MEMORY_SCOPE_AGENT) < target)
      __builtin_amdgcn_s_sleep(1);
    __threadfence();
  }
  __syncthreads();
}

// per-half (256-thread) tree reduce; both halves run symmetrically
__device__ __forceinline__ float halfReduce(float v, float* red, int half, int tid) {
  red[half * 256 + tid] = v; __syncthreads();
  #pragma unroll
  for (int st = 128; st > 0; st >>= 1) {
    if (tid < st) red[half * 256 + tid] += red[half * 256 + tid + st];
    __syncthreads();
  }
  float r = red[half * 256];
  __syncthreads();
  return r;
}

// ---------------- MFMA GEMM phase (device function, 512 threads / 8 waves) ----------------
// A [M][K] bf16, W [N][K] bf16. Block tile 64 x (JF*32), BK=64.
// JF=2: wave tile 16x32 (8 waves = 64x64).  JF=1: wave tile 16x16 (8 waves = 64x32).
// EPI: 0 bias+relu->f32 | 1 relu*aux->bf16 | 2 raw->outf+partoff | 3 relu+aux->f32
template<int JF, int EPI>
__device__ __forceinline__ void gemm_phase(
    const unsigned short* __restrict__ A, const unsigned short* __restrict__ W,
    const float* __restrict__ bias, const float* __restrict__ auxf,
    float* __restrict__ outf, unsigned short* __restrict__ outb,
    int K, int N, int m0, int n0, int k0, int nt, size_t partoff,
    unsigned short* As, unsigned short* Ws)
{
  const int t = threadIdx.x;
  const int lane = t & 63, w = t >> 6;
  const int lr = lane & 15, lk = lane >> 4;
  const int l3 = lane >> 3, cch = lane & 7;
  const int wr = (w & 3) * 16;
  const int wc = (w >> 2) * (JF * 16);
  const int BN = JF * 32;

  f32x4 acc[JF];
  #pragma unroll
  for (int j = 0; j < JF; j++) acc[j] = (f32x4){0.f, 0.f, 0.f, 0.f};

#if HAVE_GLL
  #define STG(tt)                                                                   \
    {                                                                               \
      int buf_ = (tt) & 1; int kk_ = k0 + (tt) * 64;                                \
      { int r_ = w * 8 + l3;                                                        \
        load16_lds(&A[(size_t)(m0 + r_) * K + kk_ + ((cch ^ (r_ & 7)) << 3)],       \
                   &As[buf_ * 4096 + w * 512]); }                                   \
      if (w < BN / 8) { int r_ = w * 8 + l3;                                        \
        load16_lds(&W[(size_t)(n0 + r_) * K + kk_ + ((cch ^ (r_ & 7)) << 3)],       \
                   &Ws[buf_ * 4096 + w * 512]); }                                   \
    }
  STG(0);
  for (int tt = 0; tt < nt; tt++) {
    asm volatile("s_waitcnt vmcnt(0)" ::: "memory");
    __builtin_amdgcn_s_barrier();
    asm volatile("" ::: "memory");
    if (tt + 1 < nt) STG(tt + 1);
    const unsigned short* Ab = &As[(tt & 1) * 4096];
    const unsigned short* Wb = &Ws[(tt & 1) * 4096];
    #pragma unroll
    for (int ks = 0; ks < 2; ks++) {
      int q = ks * 4 + lk;
      int r = wr + lr;
      bf16x8 af = *(const bf16x8*)&Ab[r * 64 + ((q ^ (r & 7)) << 3)];
      #pragma unroll
      for (int j = 0; j < JF; j++) {
        int c = wc + j * 16 + lr;
        bf16x8 bf = *(const bf16x8*)&Wb[c * 64 + ((q ^ (c & 7)) << 3)];
        acc[j] = __builtin_amdgcn_mfma_f32_16x16x32_bf16(af, bf, acc[j], 0, 0, 0);
      }
    }
  }
  #undef STG
#else
  for (int tt = 0; tt < nt; tt++) {
    int buf_ = tt & 1; int kk_ = k0 + tt * 64;
    int r_ = w * 8 + l3;
    bf16x8 va = *(const bf16x8*)&A[(size_t)(m0 + r_) * K + kk_ + ((cch ^ (r_ & 7)) << 3)];
    *(bf16x8*)&As[buf_ * 4096 + r_ * 64 + (cch << 3)] = va;
    if (w < BN / 8) {
      bf16x8 vw = *(const bf16x8*)&W[(size_t)(n0 + r_) * K + kk_ + ((cch ^ (r_ & 7)) << 3)];
      *(bf16x8*)&Ws[buf_ * 4096 + r_ * 64 + (cch << 3)] = vw;
    }
    __syncthreads();
    const unsigned short* Ab = &As[buf_ * 4096];
    const unsigned short* Wb = &Ws[buf_ * 4096];
    #pragma unroll
    for (int ks = 0; ks < 2; ks++) {
      int q = ks * 4 + lk;
      int r = wr + lr;
      bf16x8 af = *(const bf16x8*)&Ab[r * 64 + ((q ^ (r & 7)) << 3)];
      #pragma unroll
      for (int j = 0; j < JF; j++) {
        int c = wc + j * 16 + lr;
        bf16x8 bf = *(const bf16x8*)&Wb[c * 64 + ((q ^ (c & 7)) << 3)];
        acc[j] = __builtin_amdgcn_mfma_f32_16x16x32_bf16(af, bf, acc[j], 0, 0, 0);
      }
    }
    __syncthreads();
  }
#endif

  #pragma unroll
  for (int j = 0; j < JF; j++) {
    #pragma unroll
    for (int q = 0; q < 4; q++) {
      int r = m0 + wr + lk * 4 + q;
      int c = n0 + wc + j * 16 + lr;
      float v = acc[j][q];
      if (EPI == 0) {
        v += bias[c]; v = fmaxf(v, 0.f);
        outf[(size_t)r * N + c] = v;
      } else if (EPI == 1) {
        v = fmaxf(v, 0.f) * auxf[(size_t)r * N + c];
        outb[(size_t)r * N + c] = f2b(v);
      } else if (EPI == 2) {
        outf[partoff + (size_t)r * N + c] = v;
      } else {
        v = fmaxf(v, 0.f) + auxf[(size_t)r * N + c];
        outf[(size_t)r * N + c] = v;
      }
    }
  }
}

// ---------------- step_a phase: 2 rows per block ----------------
__device__ __forceinline__ void phase_step_a(
    int blk, const float* __restrict__ x, float* __restrict__ xw,
    const float* __restrict__ zh, const float* __restrict__ bybx,
    const float* lna_g, const float* lna_b, float lam, int k,
    unsigned short* __restrict__ acond_bf, float* red, float* dots)
{
  const int t = threadIdx.x;
  const int tid = t & 255, half = t >> 8;
  const int b = blk * 2 + half;
  const int lane = tid & 63, hd = tid >> 6;
  const float* xb = x + (size_t)b * NTOT_;
  float xv[8];
  #pragma unroll
  for (int i = 0; i < 8; i++) xv[i] = xb[tid * 8 + i];

  if (k >= 1) {
    float s = 0.f;
    #pragma unroll
    for (int i = 0; i < 8; i++) s += xv[i] * xv[i];
    #pragma unroll
    for (int m = 1; m < 64; m <<= 1) s += __shfl_xor(s, m, 64);
    float inv = 1.f / (sqrtf(s) + 1e-8f);
    float* xwo = xw + ((size_t)(k - 1) * B_ + b) * NTOT_;
    #pragma unroll
    for (int i = 0; i < 8; i++) xwo[tid * 8 + i] = xv[i] * inv;
    if (lane == 0) dots[half * 32 + (k - 1) * 4 + hd] = s * inv;
  }
  for (int j = 0; j < k - 1; j++) {
    const float* xwb = xw + ((size_t)j * B_ + b) * NTOT_;
    float s = 0.f;
    #pragma unroll
    for (int i = 0; i < 8; i++) s += xv[i] * xwb[tid * 8 + i];
    #pragma unroll
    for (int off = 32; off > 0; off >>= 1) s += __shfl_down(s, off, 64);
    if (lane == 0) dots[half * 32 + j * 4 + hd] = s;
  }
  __syncthreads();

  int d = tid;
  float av = 0.f, lp = 1.f;
  for (int j = k - 1; j >= 0; j--) {
    av += (1.f - lam) * lp * dots[half * 32 + j * 4 + (d >> 6)] *
          zh[((size_t)j * B_ + b) * D_ + d];
    lp *= lam;
  }
  av += bybx[(size_t)b * 512 + d];
  float mu = halfReduce(av, red, half, tid) * (1.f / 256.f);
  float c = av - mu;
  float var = halfReduce(c * c, red, half, tid) * (1.f / 256.f);
  acond_bf[(size_t)b * D_ + d] = f2b(c * rsqrtf(var + 1e-5f) * lna_g[d] + lna_b[d]);
}

// ---------------- LN phase (zparts sum -> zh[k], zbx_bf) ----------------
__device__ __forceinline__ void phase_ln(
    int blk, int k, const float* __restrict__ zparts, const float* __restrict__ bybx,
    const float* lnz_g, const float* lnz_b, float* __restrict__ zh,
    unsigned short* __restrict__ zbx_bf, float* red)
{
  const int t = threadIdx.x, tid = t & 255, half = t >> 8;
  const int b = blk * 2 + half, d = tid;
  float v = 0.f;
  #pragma unroll
  for (int p = 0; p < 4; p++) v += zparts[(size_t)p * (B_ * D_) + (size_t)b * D_ + d];
  float mu = halfReduce(v, red, half, tid) * (1.f / 256.f);
  float c = v - mu;
  float var = halfReduce(c * c, red, half, tid) * (1.f / 256.f);
  float vn = c * rsqrtf(var + 1e-5f) * lnz_g[d] + lnz_b[d];
  zh[((size_t)k * B_ + b) * D_ + d] = vn;
  zbx_bf[(size_t)b * D_ + d] = f2b(vn + bybx[(size_t)b * 512 + 256 + d]);
}

// ---------------- value head phase ----------------
__device__ __forceinline__ void phase_value(
    int blk, const float* __restrict__ z, const float* __restrict__ w1,
    const float* __restrict__ b1, const float* __restrict__ w2,
    const float* __restrict__ b2, float* __restrict__ out, float* red)
{
  const int t = threadIdx.x, tid = t & 255, half = t >> 8;
  const int b = blk * 2 + half;
  const int j = tid & 127, ih = tid >> 7;
  const float* zr = z + (size_t)b * 256;
  float s = 0.f;
  #pragma unroll 4
  for (int i = ih * 128; i < ih * 128 + 128; i++) s += zr[i] * w1[(size_t)i * 128 + j];
  red[half * 256 + tid] = s; __syncthreads();
  if (tid < 128) {
    float sv = red[half * 256 + tid] + red[half * 256 + tid + 128] + b1[j];
    red[half * 256 + tid] = gelu_exact(sv) * w2[tid];
  }
  __syncthreads();
  #pragma unroll
  for (int st = 64; st > 0; st >>= 1) {
    if (tid < st) red[half * 256 + tid] += red[half * 256 + tid + st];
    __syncthreads();
  }
  if (tid == 0) out[b] = tanhf(red[half * 256] + b2[0]);
}

// ---------------- the fused loop kernel ----------------
__global__ __launch_bounds__(512, 2) void k_loop(
    const unsigned short* __restrict__ bvec_bf, const unsigned short* __restrict__ xinitT,
    const unsigned short* __restrict__ DyT, const unsigned short* __restrict__ DxT,
    const unsigned short* __restrict__ ET,
    const float* __restrict__ xinit_b, const float* __restrict__ bybx,
    const float* __restrict__ lna_g, const float* __restrict__ lna_b,
    const float* __restrict__ lnz_g, const float* __restrict__ lnz_b,
    const float* __restrict__ log_damp,
    const float* __restrict__ vh_w1, const float* __restrict__ vh_b1,
    const float* __restrict__ vh_w2, const float* __restrict__ vh_b2,
    float* __restrict__ x, float* __restrict__ xw, float* __restrict__ zh,
    float* __restrict__ zparts, unsigned short* __restrict__ acond_bf,
    unsigned short* __restrict__ y_bf, unsigned short* __restrict__ zbx_bf,
    float* __restrict__ out, unsigned* __restrict__ bar)
{
  __shared__ __align__(16) unsigned short As[2 * 4096];
  __shared__ __align__(16) unsigned short Ws[2 * 4096];
  __shared__ float red[512];
  __shared__ float dots[64];
  const int blk = blockIdx.x;
  const int mt = (blk >> 5) * 64;
  const int n64 = (blk & 31) * 64;
  const int rem = blk & 31;
  const int nz = (rem >> 2) * 32, kz = rem & 3;
  unsigned bi = 0;
  const float lam = 1.f / (1.f + expf(-log_damp[0]));

  // x0 = relu(bvec @ xinit_w + b)
  gemm_phase<2, 0>(bvec_bf, xinitT, xinit_b, nullptr, x, nullptr,
                   256, 2048, mt, n64, 0, 4, 0, As, Ws);
  gridbar(bar, bi++);

  for (int k = 0; k < KSTEPS; k++) {
    phase_step_a(blk, x, xw, zh, bybx, lna_g, lna_b, lam, k, acond_bf, red, dots);
    gridbar(bar, bi++);
    // y = relu(acond @ D_y) * x -> bf16
    gemm_phase<2, 1>(acond_bf, DyT, nullptr, x, nullptr, y_bf,
                     256, 2048, mt, n64, 0, 4, 0, As, Ws);
    gridbar(bar, bi++);
    // zparts = y @ E (split-K 4)
    gemm_phase<1, 2>(y_bf, ET, nullptr, nullptr, zparts, nullptr,
                     2048, 256, mt, nz, kz * 512, 8, (size_t)kz * (B_ * D_), As, Ws);
    gridbar(bar, bi++);
    phase_ln(blk, k, zparts, bybx, lnz_g, lnz_b, zh, zbx_bf, red);
    gridbar(bar, bi++);
    if (k < KSTEPS - 1) {
      // x += relu(zbx @ D_x)
      gemm_phase<2, 3>(zbx_bf, DxT, nullptr, x, x, nullptr,
                       256, 2048, mt, n64, 0, 4, 0, As, Ws);
      gridbar(bar, bi++);
    }
  }
  phase_value(blk, zh + (size_t)(KSTEPS - 1) * B_ * D_, vh_w1, vh_b1, vh_w2, vh_b2, out, red);
}

// ---------------- f32 tiled GEMM (encoder only) ----------------
template<int ACT>
__global__ __launch_bounds__(256) void gemm_tile(
    const float* __restrict__ A, const float* __restrict__ W,
    const float* __restrict__ bias, float* __restrict__ out,
    unsigned short* __restrict__ outb, int M, int N, int K, int kchunk)
{
  __shared__ float As[16][68];
  __shared__ float Bs[16][68];
  const int tid = threadIdx.x;
  const int row0 = blockIdx.y * 64;
  const int col0 = blockIdx.x * 64;
  const int k0 = blockIdx.z * kchunk;
  const int ty = tid >> 4, tx = tid & 15;
  const int ar = tid >> 4, ak = tid & 15;
  const int br = tid >> 6, bc = tid & 63;
  float acc[4][4] = {};
  for (int kk = k0; kk < k0 + kchunk; kk += 16) {
    #pragma unroll
    for (int i = 0; i < 4; i++) {
      int r = ar + i * 16;
      As[ak][r] = A[(size_t)(row0 + r) * K + kk + ak];
    }
    #pragma unroll
    for (int i = 0; i < 4; i++) {
      int kr = br + i * 4;
      Bs[kr][bc] = W[(size_t)(kk + kr) * N + col0 + bc];
    }
    __syncthreads();
    #pragma unroll
    for (int q = 0; q < 16; q++) {
      float4 av = *(const float4*)&As[q][ty * 4];
      float4 bv = *(const float4*)&Bs[q][tx * 4];
      float aa[4] = {av.x, av.y, av.z, av.w};
      float bb[4] = {bv.x, bv.y, bv.z, bv.w};
      #pragma unroll
      for (int i = 0; i < 4; i++)
        #pragma unroll
        for (int j = 0; j < 4; j++)
          acc[i][j] = fmaf(aa[i], bb[j], acc[i][j]);
    }
    __syncthreads();
  }
  const bool parts = (gridDim.z > 1);
  float* o = out + (parts ? (size_t)blockIdx.z * (size_t)M * N : (size_t)0);
  #pragma unroll
  for (int i = 0; i < 4; i++) {
    int r = row0 + ty * 4 + i;
    #pragma unroll
    for (int j = 0; j < 4; j++) {
      int c = col0 + tx * 4 + j;
      float v = acc[i][j];
      if (!parts) {
        if (bias) v += bias[c];
        if (ACT == 2) v = gelu_exact(v);
      }
      o[(size_t)r * N + c] = v;
      if (!parts && outb) outb[(size_t)r * N + c] = f2b(v);
    }
  }
}

// ---------------- weight prep: transposes + Wcat + barrier init ----------------
__global__ __launch_bounds__(256) void k_prep(
    const float* __restrict__ D_y, const float* __restrict__ D_x,
    const float* __restrict__ xinit_w, const float* __restrict__ E,
    const float* __restrict__ By_w, const float* __restrict__ Bx_w,
    unsigned short* __restrict__ DyT, unsigned short* __restrict__ DxT,
    unsigned short* __restrict__ xinitT, unsigned short* __restrict__ ET,
    float* __restrict__ Wcat, unsigned* __restrict__ bar)
{
  const int t = threadIdx.x;
  if (blockIdx.y == 4) {
    if (blockIdx.x == 0 && t == 0) *bar = 0u;
    if (blockIdx.x >= 32) return;
    int k0 = ((int)blockIdx.x >> 3) * 64, n0 = ((int)blockIdx.x & 7) * 64;
    for (int i = 0; i < 16; i++) {
      int local = i * 256 + t;
      int kk = local >> 6, nn = local & 63;
      int n = n0 + nn;
      float v = (n < 256) ? By_w[(size_t)(k0 + kk) * 256 + n]
                          : Bx_w[(size_t)(k0 + kk) * 256 + (n - 256)];
      Wcat[(size_t)(k0 + kk) * 512 + n] = v;
    }
    return;
  }
  __shared__ float T[64][65];
  const float* in; unsigned short* out; int Kd, Nd, head, nx;
  switch (blockIdx.y) {
    case 0:  in = D_y;     out = DyT;    Kd = 256;  Nd = 2048; head = 1; nx = 32; break;
    case 1:  in = D_x;     out = DxT;    Kd = 256;  Nd = 2048; head = 1; nx = 32; break;
    case 2:  in = xinit_w; out = xinitT; Kd = 256;  Nd = 2048; head = 0; nx = 32; break;
    default: in = E;       out = ET;     Kd = 2048; Nd = 256;  head = 0; nx = 4;  break;
  }
  const int n0 = ((int)blockIdx.x % nx) * 64, k0 = ((int)blockIdx.x / nx) * 64;
  const int tx = t & 63, ty = t >> 6;
  #pragma unroll
  for (int i = 0; i < 16; i++) {
    int k = k0 + ty + i * 4;
    int n = n0 + tx;
    float v;
    if (head) v = in[((size_t)(n >> 9) * 256 + k) * 512 + (n & 511)];
    else      v = in[(size_t)k * Nd + n];
    T[ty + i * 4][tx] = v;
  }
  __syncthreads();
  #pragma unroll
  for (int i = 0; i < 16; i++) {
    int n = n0 + ty + i * 4;
    out[(size_t)n * Kd + k0 + tx] = f2b(T[tx][ty + i * 4]);
  }
}

// ---------------- encoder LN ----------------
__global__ __launch_bounds__(256) void k_ln_enc(
    const float* __restrict__ in, int nparts, int stride,
    const float* __restrict__ pre_bias,
    const float* __restrict__ g, const float* __restrict__ bta,
    float* __restrict__ out)
{
  __shared__ float red[256];
  int b = blockIdx.x, d = threadIdx.x;
  float v = 0.f;
  for (int p = 0; p < nparts; p++) v += in[(size_t)p * stride + (size_t)b * 256 + d];
  v = gelu_exact(v + pre_bias[d]);
  red[d] = v; __syncthreads();
  #pragma unroll
  for (int st = 128; st > 0; st >>= 1) { if (d < st) red[d] += red[d + st]; __syncthreads(); }
  float mu = red[0] * (1.f / 256.f); __syncthreads();
  float c = v - mu;
  red[d] = c * c; __syncthreads();
  #pragma unroll
  for (int st = 128; st > 0; st >>= 1) { if (d < st) red[d] += red[d + st]; __syncthreads(); }
  float var = red[0] * (1.f / 256.f);
  out[(size_t)b * 256 + d] = c * rsqrtf(var + 1e-5f) * g[d] + bta[d];
}

extern "C" void kernel_launch(void* const* d_in, const int* in_sizes, int n_in,
                              void* d_out, int out_size, void* d_ws, size_t ws_size,
                              hipStream_t stream) {
  const float* boards   = (const float*)d_in[0];
  const float* enc_w1   = (const float*)d_in[1];
  const float* enc_b1   = (const float*)d_in[2];
  const float* enc_ln_g = (const float*)d_in[3];
  const float* enc_ln_b = (const float*)d_in[4];
  const float* enc_w2   = (const float*)d_in[5];
  const float* enc_b2   = (const float*)d_in[6];
  const float* xinit_w  = (const float*)d_in[7];
  const float* xinit_b  = (const float*)d_in[8];
  const float* D_y      = (const float*)d_in[9];
  const float* E        = (const float*)d_in[10];
  const float* D_x      = (const float*)d_in[11];
  const float* By_w     = (const float*)d_in[12];
  const float* Bx_w     = (const float*)d_in[13];
  const float* lna_g    = (const float*)d_in[14];
  const float* lna_b    = (const float*)d_in[15];
  const float* lnz_g    = (const float*)d_in[16];
  const float* lnz_b    = (const float*)d_in[17];
  const float* log_damp = (const float*)d_in[18];
  const float* vh_w1    = (const float*)d_in[19];
  const float* vh_b1    = (const float*)d_in[20];
  const float* vh_w2    = (const float*)d_in[21];
  const float* vh_b2    = (const float*)d_in[22];
  float* outp = (float*)d_out;

  float* ws = (float*)d_ws;
  size_t o = 0;
  float* x      = ws + o; o += (size_t)B_ * NTOT_;
  float* xw     = ws + o; o += (size_t)KSTEPS * B_ * NTOT_;
  float* zh     = ws + o; o += (size_t)KSTEPS * B_ * D_;
  float* hparts = ws + o; o += (size_t)8 * B_ * D_;
  float* h      = ws + o; o += (size_t)B_ * D_;
  float* bvec   = ws + o; o += (size_t)B_ * D_;
  float* bybx   = ws + o; o += (size_t)B_ * 512;
  float* Wcat   = ws + o; o += (size_t)256 * 512;
  float* zparts = ws + o; o += (size_t)4 * B_ * D_;
  unsigned short* DyT     = (unsigned short*)(ws + o); o += (size_t)NTOT_ * D_ / 2;
  unsigned short* DxT     = (unsigned short*)(ws + o); o += (size_t)NTOT_ * D_ / 2;
  unsigned short* ET      = (unsigned short*)(ws + o); o += (size_t)D_ * NTOT_ / 2;
  unsigned short* xinitT  = (unsigned short*)(ws + o); o += (size_t)NTOT_ * D_ / 2;
  unsigned short* bvec_bf = (unsigned short*)(ws + o); o += (size_t)B_ * D_ / 2;
  unsigned short* acond_bf= (unsigned short*)(ws + o); o += (size_t)B_ * D_ / 2;
  unsigned short* zbx_bf  = (unsigned short*)(ws + o); o += (size_t)B_ * D_ / 2;
  unsigned short* y_bf    = (unsigned short*)(ws + o); o += (size_t)B_ * NTOT_ / 2;
  unsigned* bar           = (unsigned*)(ws + o); o += 64;

  // 1. weight prep (transposes, Wcat, barrier reset)
  k_prep<<<dim3(128, 5), 256, 0, stream>>>(D_y, D_x, xinit_w, E, By_w, Bx_w,
                                           DyT, DxT, xinitT, ET, Wcat, bar);
  // 2. enc1: boards @ enc_w1 (split-K 8)
  gemm_tile<0><<<dim3(4, 8, 8), 256, 0, stream>>>(boards, enc_w1, nullptr, hparts,
                                                  nullptr, B_, D_, 768, 96);
  // 3. h = LN(gelu(enc1 + b1))
  k_ln_enc<<<B_, 256, 0, stream>>>(hparts, 8, B_ * D_, enc_b1, enc_ln_g, enc_ln_b, h);
  // 4. bvec = h @ enc_w2 + b2 (+ bf16 copy)
  gemm_tile<0><<<dim3(4, 8, 1), 256, 0, stream>>>(h, enc_w2, enc_b2, bvec, bvec_bf,
                                                  B_, D_, D_, D_);
  // 5. [b_y | b_x] = bvec @ [By_w | Bx_w]
  gemm_tile<0><<<dim3(8, 8, 1), 256, 0, stream>>>(bvec, Wcat, nullptr, bybx, nullptr,
                                                  B_, 512, D_, D_);
  // 6. fused loop: x0, 8 thinking steps, value head
  k_loop<<<NBLK, 512, 0, stream>>>(bvec_bf, xinitT, DyT, DxT, ET, xinit_b, bybx,
                                   lna_g, lna_b, lnz_g, lnz_b, log_damp,
                                   vh_w1, vh_b1, vh_w2, vh_b2,
                                   x, xw, zh, zparts, acond_bf, y_bf, zbx_bf,
                                   outp, bar);
}

// Round 6
// 388.996 us; speedup vs baseline: 2.9505x; 2.9505x over previous
//
#include <hip/hip_runtime.h>
#include <hip/hip_bf16.h>
#include <math.h>

#define B_ 512
#define D_ 256
#define NH_ 4
#define NN_ 512
#define NTOT_ 2048
#define DH_ 64
#define KSTEPS 8

typedef __attribute__((ext_vector_type(8))) short bf16x8;
typedef __attribute__((ext_vector_type(4))) float f32x4;

#if __has_builtin(__builtin_amdgcn_global_load_lds)
#define HAVE_GLL 1
#else
#define HAVE_GLL 0
#endif

__device__ __forceinline__ float gelu_exact(float x) {
  return 0.5f * x * (1.0f + erff(x * 0.70710678118654752f));
}

__device__ __forceinline__ unsigned short f2b(float f) {
  union { float f; unsigned int u; } x; x.f = f;
  unsigned int u = x.u;
  unsigned int r = (u + 0x7FFFu + ((u >> 16) & 1u)) >> 16;
  return (unsigned short)r;
}

__device__ __forceinline__ float blockReduceSum256(float v, float* red) {
  int t = threadIdx.x;
  red[t] = v; __syncthreads();
  #pragma unroll
  for (int st = 128; st > 0; st >>= 1) {
    if (t < st) red[t] += red[t + st];
    __syncthreads();
  }
  float r = red[0];
  __syncthreads();
  return r;
}

#if HAVE_GLL
__device__ __forceinline__ void load16_lds(const unsigned short* g, unsigned short* l) {
  __builtin_amdgcn_global_load_lds(
      (const __attribute__((address_space(1))) unsigned int*)g,
      (__attribute__((address_space(3))) unsigned int*)l, 16, 0, 0);
}
#endif

// ---------------- x-GEMM: 64x64 tile, K=256, N=2048, 512 threads ----------------
// EPI 0: xio = relu(A@W^T + bias)   (x0)
// EPI 1: xio += relu(A@W^T)         (x update, in-place on own tile)
template<int EPI>
__global__ __launch_bounds__(512) void k_gemm_x(
    const unsigned short* __restrict__ A, const unsigned short* __restrict__ W,
    const float* __restrict__ bias, float* __restrict__ xio)
{
  __shared__ __align__(16) unsigned short As[2 * 4096];
  __shared__ __align__(16) unsigned short Ws[2 * 4096];
  const int t = threadIdx.x;
  const int lane = t & 63, w = t >> 6;
  const int lr = lane & 15, lk = lane >> 4;
  const int l3 = lane >> 3, cch = lane & 7;
  const int n0 = blockIdx.x * 64, m0 = blockIdx.y * 64;
  const int wm = w & 3, wn = w >> 2;

  f32x4 acc[2];
  acc[0] = (f32x4){0.f, 0.f, 0.f, 0.f};
  acc[1] = (f32x4){0.f, 0.f, 0.f, 0.f};

#if HAVE_GLL
  #define STGX(tt) {                                                              \
      int buf_ = (tt) & 1; int kk_ = (tt) * 64;                                   \
      int r_ = w * 8 + l3;                                                        \
      load16_lds(&A[(size_t)(m0 + r_) * 256 + kk_ + ((cch ^ (r_ & 7)) << 3)],     \
                 &As[buf_ * 4096 + w * 512]);                                     \
      load16_lds(&W[(size_t)(n0 + r_) * 256 + kk_ + ((cch ^ (r_ & 7)) << 3)],     \
                 &Ws[buf_ * 4096 + w * 512]); }
  STGX(0);
  for (int tt = 0; tt < 4; tt++) {
    asm volatile("s_waitcnt vmcnt(0)" ::: "memory");
    __builtin_amdgcn_s_barrier();
    asm volatile("" ::: "memory");
    if (tt + 1 < 4) STGX(tt + 1);
    const unsigned short* Ab = &As[(tt & 1) * 4096];
    const unsigned short* Wb = &Ws[(tt & 1) * 4096];
    #pragma unroll
    for (int ks = 0; ks < 2; ks++) {
      int q = ks * 4 + lk;
      int r = wm * 16 + lr;
      bf16x8 af = *(const bf16x8*)&Ab[r * 64 + ((q ^ (r & 7)) << 3)];
      #pragma unroll
      for (int j = 0; j < 2; j++) {
        int c = wn * 32 + j * 16 + lr;
        bf16x8 bf = *(const bf16x8*)&Wb[c * 64 + ((q ^ (c & 7)) << 3)];
        acc[j] = __builtin_amdgcn_mfma_f32_16x16x32_bf16(af, bf, acc[j], 0, 0, 0);
      }
    }
  }
  #undef STGX
#else
  for (int tt = 0; tt < 4; tt++) {
    int buf_ = tt & 1; int kk_ = tt * 64;
    int r_ = w * 8 + l3;
    bf16x8 va = *(const bf16x8*)&A[(size_t)(m0 + r_) * 256 + kk_ + ((cch ^ (r_ & 7)) << 3)];
    *(bf16x8*)&As[buf_ * 4096 + r_ * 64 + cch * 8] = va;
    bf16x8 vw = *(const bf16x8*)&W[(size_t)(n0 + r_) * 256 + kk_ + ((cch ^ (r_ & 7)) << 3)];
    *(bf16x8*)&Ws[buf_ * 4096 + r_ * 64 + cch * 8] = vw;
    __syncthreads();
    const unsigned short* Ab = &As[buf_ * 4096];
    const unsigned short* Wb = &Ws[buf_ * 4096];
    #pragma unroll
    for (int ks = 0; ks < 2; ks++) {
      int q = ks * 4 + lk;
      int r = wm * 16 + lr;
      bf16x8 af = *(const bf16x8*)&Ab[r * 64 + ((q ^ (r & 7)) << 3)];
      #pragma unroll
      for (int j = 0; j < 2; j++) {
        int c = wn * 32 + j * 16 + lr;
        bf16x8 bf = *(const bf16x8*)&Wb[c * 64 + ((q ^ (c & 7)) << 3)];
        acc[j] = __builtin_amdgcn_mfma_f32_16x16x32_bf16(af, bf, acc[j], 0, 0, 0);
      }
    }
    __syncthreads();
  }
#endif

  #pragma unroll
  for (int j = 0; j < 2; j++)
    #pragma unroll
    for (int qq = 0; qq < 4; qq++) {
      int r = m0 + wm * 16 + lk * 4 + qq;
      int c = n0 + wn * 32 + j * 16 + lr;
      float v = acc[j][qq];
      if (EPI == 0) v = fmaxf(v + bias[c], 0.f);
      else          v = fmaxf(v, 0.f) + xio[(size_t)r * NTOT_ + c];
      xio[(size_t)r * NTOT_ + c] = v;
    }
}

// ---------------- fused y@Dy + z-partial kernel ----------------
// Block (nt, mt): y_tile[64x64] = relu(acond[m-rows]@DyT[n-cols]) * x  -> LDS bf16
// then zpart[nt][m-rows][256] = y_tile @ E[n-slice]  (ET staged via async LDS)
__global__ __launch_bounds__(512) void k_yz(
    const unsigned short* __restrict__ acond_bf, const unsigned short* __restrict__ DyT,
    const unsigned short* __restrict__ ET, const float* __restrict__ x,
    float* __restrict__ zparts)
{
  __shared__ __align__(16) unsigned short As[2 * 4096];
  __shared__ __align__(16) unsigned short Ws[2 * 4096];
  __shared__ __align__(16) unsigned short Es[256 * 64];
  __shared__ __align__(16) unsigned short ytile[64 * 64];
  const int t = threadIdx.x;
  const int lane = t & 63, w = t >> 6;
  const int lr = lane & 15, lk = lane >> 4;
  const int l3 = lane >> 3, cch = lane & 7;
  const int nt_ = blockIdx.x, mt = blockIdx.y;
  const int m0 = mt * 64, n0 = nt_ * 64;
  const int wm = w & 3, wn = w >> 2;

  f32x4 acc[2];
  acc[0] = (f32x4){0.f, 0.f, 0.f, 0.f};
  acc[1] = (f32x4){0.f, 0.f, 0.f, 0.f};

#if HAVE_GLL
  #define STGY(tt) {                                                                  \
      int buf_ = (tt) & 1; int kk_ = (tt) * 64;                                       \
      int r_ = w * 8 + l3;                                                            \
      load16_lds(&acond_bf[(size_t)(m0 + r_) * 256 + kk_ + ((cch ^ (r_ & 7)) << 3)],  \
                 &As[buf_ * 4096 + w * 512]);                                         \
      load16_lds(&DyT[(size_t)(n0 + r_) * 256 + kk_ + ((cch ^ (r_ & 7)) << 3)],       \
                 &Ws[buf_ * 4096 + w * 512]); }
  STGY(0);
  // stage E^T slice [256 d-rows][64 k-cols] early; drained by first vmcnt(0)
  #pragma unroll
  for (int p = 0; p < 4; p++) {
    int d = p * 64 + w * 8 + l3;
    load16_lds(&ET[(size_t)d * 2048 + n0 + ((cch ^ (d & 7)) << 3)],
               &Es[(p * 64 + w * 8) * 64]);
  }
  for (int tt = 0; tt < 4; tt++) {
    asm volatile("s_waitcnt vmcnt(0)" ::: "memory");
    __builtin_amdgcn_s_barrier();
    asm volatile("" ::: "memory");
    if (tt + 1 < 4) STGY(tt + 1);
    const unsigned short* Ab = &As[(tt & 1) * 4096];
    const unsigned short* Wb = &Ws[(tt & 1) * 4096];
    #pragma unroll
    for (int ks = 0; ks < 2; ks++) {
      int q = ks * 4 + lk;
      int r = wm * 16 + lr;
      bf16x8 af = *(const bf16x8*)&Ab[r * 64 + ((q ^ (r & 7)) << 3)];
      #pragma unroll
      for (int j = 0; j < 2; j++) {
        int c = wn * 32 + j * 16 + lr;
        bf16x8 bf = *(const bf16x8*)&Wb[c * 64 + ((q ^ (c & 7)) << 3)];
        acc[j] = __builtin_amdgcn_mfma_f32_16x16x32_bf16(af, bf, acc[j], 0, 0, 0);
      }
    }
  }
  #undef STGY
#else
  // fallback: reg staging
  #pragma unroll
  for (int p = 0; p < 4; p++) {
    int d = p * 64 + w * 8 + l3;
    bf16x8 ve = *(const bf16x8*)&ET[(size_t)d * 2048 + n0 + ((cch ^ (d & 7)) << 3)];
    *(bf16x8*)&Es[d * 64 + cch * 8] = ve;
  }
  for (int tt = 0; tt < 4; tt++) {
    int buf_ = tt & 1; int kk_ = tt * 64;
    int r_ = w * 8 + l3;
    bf16x8 va = *(const bf16x8*)&acond_bf[(size_t)(m0 + r_) * 256 + kk_ + ((cch ^ (r_ & 7)) << 3)];
    *(bf16x8*)&As[buf_ * 4096 + r_ * 64 + cch * 8] = va;
    bf16x8 vw = *(const bf16x8*)&DyT[(size_t)(n0 + r_) * 256 + kk_ + ((cch ^ (r_ & 7)) << 3)];
    *(bf16x8*)&Ws[buf_ * 4096 + r_ * 64 + cch * 8] = vw;
    __syncthreads();
    const unsigned short* Ab = &As[buf_ * 4096];
    const unsigned short* Wb = &Ws[buf_ * 4096];
    #pragma unroll
    for (int ks = 0; ks < 2; ks++) {
      int q = ks * 4 + lk;
      int r = wm * 16 + lr;
      bf16x8 af = *(const bf16x8*)&Ab[r * 64 + ((q ^ (r & 7)) << 3)];
      #pragma unroll
      for (int j = 0; j < 2; j++) {
        int c = wn * 32 + j * 16 + lr;
        bf16x8 bf = *(const bf16x8*)&Wb[c * 64 + ((q ^ (c & 7)) << 3)];
        acc[j] = __builtin_amdgcn_mfma_f32_16x16x32_bf16(af, bf, acc[j], 0, 0, 0);
      }
    }
    __syncthreads();
  }
#endif

  // y epilogue: relu * x -> bf16 into swizzled ytile
  #pragma unroll
  for (int j = 0; j < 2; j++)
    #pragma unroll
    for (int qq = 0; qq < 4; qq++) {
      int rl = wm * 16 + lk * 4 + qq;
      int cl = wn * 32 + j * 16 + lr;
      float v = fmaxf(acc[j][qq], 0.f) * x[(size_t)(m0 + rl) * NTOT_ + n0 + cl];
      ytile[rl * 64 + ((((cl >> 3) ^ (rl & 7)) << 3) | (cl & 7))] = f2b(v);
    }
  __syncthreads();

  // z phase: [64 rows] x [256 d] over K=64
  f32x4 zacc[8];
  #pragma unroll
  for (int j = 0; j < 8; j++) zacc[j] = (f32x4){0.f, 0.f, 0.f, 0.f};
  #pragma unroll
  for (int ks = 0; ks < 2; ks++) {
    int q = ks * 4 + lk;
    int r = wm * 16 + lr;
    bf16x8 af = *(const bf16x8*)&ytile[r * 64 + ((q ^ (r & 7)) << 3)];
    #pragma unroll
    for (int j = 0; j < 8; j++) {
      int c = wn * 128 + j * 16 + lr;
      bf16x8 bf = *(const bf16x8*)&Es[c * 64 + ((q ^ (c & 7)) << 3)];
      zacc[j] = __builtin_amdgcn_mfma_f32_16x16x32_bf16(af, bf, zacc[j], 0, 0, 0);
    }
  }
  float* zp = zparts + (size_t)nt_ * (B_ * D_);
  #pragma unroll
  for (int j = 0; j < 8; j++)
    #pragma unroll
    for (int qq = 0; qq < 4; qq++) {
      int r = m0 + wm * 16 + lk * 4 + qq;
      int d = wn * 128 + j * 16 + lr;
      zp[(size_t)r * D_ + d] = zacc[j][qq];
    }
}

// ---------------- f32 tiled GEMM (encoder only) ----------------
template<int ACT>
__global__ __launch_bounds__(256) void gemm_tile(
    const float* __restrict__ A, const float* __restrict__ W,
    const float* __restrict__ bias, float* __restrict__ out,
    unsigned short* __restrict__ outb, int M, int N, int K, int kchunk)
{
  __shared__ float As[16][68];
  __shared__ float Bs[16][68];
  const int tid = threadIdx.x;
  const int row0 = blockIdx.y * 64;
  const int col0 = blockIdx.x * 64;
  const int k0 = blockIdx.z * kchunk;
  const int ty = tid >> 4, tx = tid & 15;
  const int ar = tid >> 4, ak = tid & 15;
  const int br = tid >> 6, bc = tid & 63;
  float acc[4][4] = {};
  for (int kk = k0; kk < k0 + kchunk; kk += 16) {
    #pragma unroll
    for (int i = 0; i < 4; i++) {
      int r = ar + i * 16;
      As[ak][r] = A[(size_t)(row0 + r) * K + kk + ak];
    }
    #pragma unroll
    for (int i = 0; i < 4; i++) {
      int kr = br + i * 4;
      Bs[kr][bc] = W[(size_t)(kk + kr) * N + col0 + bc];
    }
    __syncthreads();
    #pragma unroll
    for (int q = 0; q < 16; q++) {
      float4 av = *(const float4*)&As[q][ty * 4];
      float4 bv = *(const float4*)&Bs[q][tx * 4];
      float aa[4] = {av.x, av.y, av.z, av.w};
      float bb[4] = {bv.x, bv.y, bv.z, bv.w};
      #pragma unroll
      for (int i = 0; i < 4; i++)
        #pragma unroll
        for (int j = 0; j < 4; j++)
          acc[i][j] = fmaf(aa[i], bb[j], acc[i][j]);
    }
    __syncthreads();
  }
  const bool parts = (gridDim.z > 1);
  float* o = out + (parts ? (size_t)blockIdx.z * (size_t)M * N : (size_t)0);
  #pragma unroll
  for (int i = 0; i < 4; i++) {
    int r = row0 + ty * 4 + i;
    #pragma unroll
    for (int j = 0; j < 4; j++) {
      int c = col0 + tx * 4 + j;
      float v = acc[i][j];
      if (!parts) {
        if (bias) v += bias[c];
        if (ACT == 2) v = gelu_exact(v);
      }
      o[(size_t)r * N + c] = v;
      if (!parts && outb) outb[(size_t)r * N + c] = f2b(v);
    }
  }
}

// ---------------- weight prep ----------------
__global__ __launch_bounds__(256) void k_prep(
    const float* __restrict__ D_y, const float* __restrict__ D_x,
    const float* __restrict__ xinit_w, const float* __restrict__ E,
    const float* __restrict__ By_w, const float* __restrict__ Bx_w,
    unsigned short* __restrict__ DyT, unsigned short* __restrict__ DxT,
    unsigned short* __restrict__ xinitT, unsigned short* __restrict__ ET,
    float* __restrict__ Wcat)
{
  const int t = threadIdx.x;
  if (blockIdx.y == 4) {
    if (blockIdx.x >= 32) return;
    int k0 = ((int)blockIdx.x >> 3) * 64, n0 = ((int)blockIdx.x & 7) * 64;
    for (int i = 0; i < 16; i++) {
      int local = i * 256 + t;
      int kk = local >> 6, nn = local & 63;
      int n = n0 + nn;
      float v = (n < 256) ? By_w[(size_t)(k0 + kk) * 256 + n]
                          : Bx_w[(size_t)(k0 + kk) * 256 + (n - 256)];
      Wcat[(size_t)(k0 + kk) * 512 + n] = v;
    }
    return;
  }
  __shared__ float T[64][65];
  const float* in; unsigned short* out; int Kd, Nd, head, nx;
  switch (blockIdx.y) {
    case 0:  in = D_y;     out = DyT;    Kd = 256;  Nd = 2048; head = 1; nx = 32; break;
    case 1:  in = D_x;     out = DxT;    Kd = 256;  Nd = 2048; head = 1; nx = 32; break;
    case 2:  in = xinit_w; out = xinitT; Kd = 256;  Nd = 2048; head = 0; nx = 32; break;
    default: in = E;       out = ET;     Kd = 2048; Nd = 256;  head = 0; nx = 4;  break;
  }
  const int n0 = ((int)blockIdx.x % nx) * 64, k0 = ((int)blockIdx.x / nx) * 64;
  const int tx = t & 63, ty = t >> 6;
  #pragma unroll
  for (int i = 0; i < 16; i++) {
    int k = k0 + ty + i * 4;
    int n = n0 + tx;
    float v;
    if (head) v = in[((size_t)(n >> 9) * 256 + k) * 512 + (n & 511)];
    else      v = in[(size_t)k * Nd + n];
    T[ty + i * 4][tx] = v;
  }
  __syncthreads();
  #pragma unroll
  for (int i = 0; i < 16; i++) {
    int n = n0 + ty + i * 4;
    out[(size_t)n * Kd + k0 + tx] = f2b(T[tx][ty + i * 4]);
  }
}

// ---------------- encoder LN ----------------
__global__ __launch_bounds__(256) void k_ln_enc(
    const float* __restrict__ in, int nparts, int stride,
    const float* __restrict__ pre_bias,
    const float* __restrict__ g, const float* __restrict__ bta,
    float* __restrict__ out)
{
  __shared__ float red[256];
  int b = blockIdx.x, d = threadIdx.x;
  float v = 0.f;
  for (int p = 0; p < nparts; p++) v += in[(size_t)p * stride + (size_t)b * 256 + d];
  v = gelu_exact(v + pre_bias[d]);
  float mu = blockReduceSum256(v, red) * (1.f / 256.f);
  float c = v - mu;
  float var = blockReduceSum256(c * c, red) * (1.f / 256.f);
  out[(size_t)b * 256 + d] = c * rsqrtf(var + 1e-5f) * g[d] + bta[d];
}

// ---------------- z-LN (+ optional fused value head) ----------------
template<int VAL>
__global__ __launch_bounds__(256) void k_ln_z(
    const float* __restrict__ zparts, const float* __restrict__ bybx,
    const float* __restrict__ lnz_g, const float* __restrict__ lnz_b,
    float* __restrict__ zh_k, unsigned short* __restrict__ zbx_bf,
    const float* __restrict__ w1, const float* __restrict__ b1,
    const float* __restrict__ w2, const float* __restrict__ b2,
    float* __restrict__ vout)
{
  __shared__ float red[256];
  __shared__ float zn[256];
  int b = blockIdx.x, d = threadIdx.x;
  float v = 0.f;
  #pragma unroll
  for (int p = 0; p < 32; p++) v += zparts[(size_t)p * (B_ * D_) + (size_t)b * D_ + d];
  float mu = blockReduceSum256(v, red) * (1.f / 256.f);
  float c = v - mu;
  float var = blockReduceSum256(c * c, red) * (1.f / 256.f);
  float vn = c * rsqrtf(var + 1e-5f) * lnz_g[d] + lnz_b[d];
  zh_k[(size_t)b * D_ + d] = vn;
  zbx_bf[(size_t)b * D_ + d] = f2b(vn + bybx[(size_t)b * 512 + 256 + d]);
  if (VAL) {
    zn[d] = vn; __syncthreads();
    int j = d & 127, ih = d >> 7;
    float s = 0.f;
    #pragma unroll 4
    for (int i = ih * 128; i < ih * 128 + 128; i++) s += zn[i] * w1[(size_t)i * 128 + j];
    red[d] = s; __syncthreads();
    if (d < 128) red[d] = gelu_exact(red[d] + red[d + 128] + b1[j]) * w2[d];
    __syncthreads();
    #pragma unroll
    for (int st = 64; st > 0; st >>= 1) {
      if (d < st) red[d] += red[d + st];
      __syncthreads();
    }
    if (d == 0) vout[b] = tanhf(red[0] + b2[0]);
  }
}

// ---------------- step_a: xw(k-1) + low-rank rho dots + LN -> acond (bf16) ----------------
__global__ __launch_bounds__(256) void k_step_a(
    const float* __restrict__ x, float* __restrict__ xw_hist,
    const float* __restrict__ z_hist, const float* __restrict__ bybx,
    const float* __restrict__ lna_g, const float* __restrict__ lna_b,
    const float* __restrict__ log_damp, int k, unsigned short* __restrict__ out)
{
  __shared__ float dots[KSTEPS][NH_];
  __shared__ float red[256];
  int b = blockIdx.x, t = threadIdx.x;
  int lane = t & 63, wv = t >> 6;
  float lam = 1.f / (1.f + expf(-log_damp[0]));
  const float* xb = x + (size_t)b * NTOT_;
  float xv[8];
  #pragma unroll
  for (int i = 0; i < 8; i++) xv[i] = xb[t * 8 + i];

  if (k >= 1) {
    float s = 0.f;
    #pragma unroll
    for (int i = 0; i < 8; i++) s += xv[i] * xv[i];
    #pragma unroll
    for (int m = 1; m < 64; m <<= 1) s += __shfl_xor(s, m, 64);
    float inv = 1.f / (sqrtf(s) + 1e-8f);
    float* xwo = xw_hist + ((size_t)(k - 1) * B_ + b) * NTOT_;
    #pragma unroll
    for (int i = 0; i < 8; i++) xwo[t * 8 + i] = xv[i] * inv;
    if (lane == 0) dots[k - 1][wv] = s * inv;
  }
  for (int j = 0; j < k - 1; j++) {
    const float* xwb = xw_hist + ((size_t)j * B_ + b) * NTOT_;
    float s = 0.f;
    #pragma unroll
    for (int i = 0; i < 8; i++) s += xv[i] * xwb[t * 8 + i];
    #pragma unroll
    for (int off = 32; off > 0; off >>= 1) s += __shfl_down(s, off, 64);
    if (lane == 0) dots[j][wv] = s;
  }
  __syncthreads();

  int d = t;
  float av = 0.f, lp = 1.f;
  for (int j = k - 1; j >= 0; j--) {
    av += (1.f - lam) * lp * dots[j][d >> 6] * z_hist[((size_t)j * B_ + b) * D_ + d];
    lp *= lam;
  }
  av += bybx[(size_t)b * 512 + d];
  float mu = blockReduceSum256(av, red) * (1.f / 256.f);
  float c = av - mu;
  float var = blockReduceSum256(c * c, red) * (1.f / 256.f);
  out[(size_t)b * D_ + d] = f2b(c * rsqrtf(var + 1e-5f) * lna_g[d] + lna_b[d]);
}

extern "C" void kernel_launch(void* const* d_in, const int* in_sizes, int n_in,
                              void* d_out, int out_size, void* d_ws, size_t ws_size,
                              hipStream_t stream) {
  const float* boards   = (const float*)d_in[0];
  const float* enc_w1   = (const float*)d_in[1];
  const float* enc_b1   = (const float*)d_in[2];
  const float* enc_ln_g = (const float*)d_in[3];
  const float* enc_ln_b = (const float*)d_in[4];
  const float* enc_w2   = (const float*)d_in[5];
  const float* enc_b2   = (const float*)d_in[6];
  const float* xinit_w  = (const float*)d_in[7];
  const float* xinit_b  = (const float*)d_in[8];
  const float* D_y      = (const float*)d_in[9];
  const float* E        = (const float*)d_in[10];
  const float* D_x      = (const float*)d_in[11];
  const float* By_w     = (const float*)d_in[12];
  const float* Bx_w     = (const float*)d_in[13];
  const float* lna_g    = (const float*)d_in[14];
  const float* lna_b    = (const float*)d_in[15];
  const float* lnz_g    = (const float*)d_in[16];
  const float* lnz_b    = (const float*)d_in[17];
  const float* log_damp = (const float*)d_in[18];
  const float* vh_w1    = (const float*)d_in[19];
  const float* vh_b1    = (const float*)d_in[20];
  const float* vh_w2    = (const float*)d_in[21];
  const float* vh_b2    = (const float*)d_in[22];
  float* outp = (float*)d_out;

  float* ws = (float*)d_ws;
  size_t o = 0;
  float* x      = ws + o; o += (size_t)B_ * NTOT_;
  float* xw     = ws + o; o += (size_t)KSTEPS * B_ * NTOT_;
  float* zh     = ws + o; o += (size_t)KSTEPS * B_ * D_;
  float* hparts = ws + o; o += (size_t)8 * B_ * D_;
  float* h      = ws + o; o += (size_t)B_ * D_;
  float* bvec   = ws + o; o += (size_t)B_ * D_;
  float* bybx   = ws + o; o += (size_t)B_ * 512;
  float* Wcat   = ws + o; o += (size_t)256 * 512;
  float* zparts = ws + o; o += (size_t)32 * B_ * D_;
  unsigned short* DyT     = (unsigned short*)(ws + o); o += (size_t)NTOT_ * D_ / 2;
  unsigned short* DxT     = (unsigned short*)(ws + o); o += (size_t)NTOT_ * D_ / 2;
  unsigned short* ET      = (unsigned short*)(ws + o); o += (size_t)D_ * NTOT_ / 2;
  unsigned short* xinitT  = (unsigned short*)(ws + o); o += (size_t)NTOT_ * D_ / 2;
  unsigned short* bvec_bf = (unsigned short*)(ws + o); o += (size_t)B_ * D_ / 2;
  unsigned short* acond_bf= (unsigned short*)(ws + o); o += (size_t)B_ * D_ / 2;
  unsigned short* zbx_bf  = (unsigned short*)(ws + o); o += (size_t)B_ * D_ / 2;

  // ---- one-time weight prep ----
  k_prep<<<dim3(128, 5), 256, 0, stream>>>(D_y, D_x, xinit_w, E, By_w, Bx_w,
                                           DyT, DxT, xinitT, ET, Wcat);
  // ---- encoder (f32) ----
  gemm_tile<0><<<dim3(4, 8, 8), 256, 0, stream>>>(boards, enc_w1, nullptr, hparts,
                                                  nullptr, B_, D_, 768, 96);
  k_ln_enc<<<B_, 256, 0, stream>>>(hparts, 8, B_ * D_, enc_b1, enc_ln_g, enc_ln_b, h);
  gemm_tile<0><<<dim3(4, 8, 1), 256, 0, stream>>>(h, enc_w2, enc_b2, bvec, bvec_bf,
                                                  B_, D_, D_, D_);
  gemm_tile<0><<<dim3(8, 8, 1), 256, 0, stream>>>(bvec, Wcat, nullptr, bybx, nullptr,
                                                  B_, 512, D_, D_);
  // x0 = relu(bvec @ xinit_w + bias)
  k_gemm_x<0><<<dim3(32, 8), 512, 0, stream>>>(bvec_bf, xinitT, xinit_b, x);

  // ---- K thinking steps ----
  for (int k = 0; k < KSTEPS; k++) {
    k_step_a<<<B_, 256, 0, stream>>>(x, xw, zh, bybx, lna_g, lna_b, log_damp, k, acond_bf);
    k_yz<<<dim3(32, 8), 512, 0, stream>>>(acond_bf, DyT, ET, x, zparts);
    if (k < KSTEPS - 1) {
      k_ln_z<0><<<B_, 256, 0, stream>>>(zparts, bybx, lnz_g, lnz_b,
                                        zh + (size_t)k * B_ * D_, zbx_bf,
                                        nullptr, nullptr, nullptr, nullptr, nullptr);
      k_gemm_x<1><<<dim3(32, 8), 512, 0, stream>>>(zbx_bf, DxT, nullptr, x);
    } else {
      k_ln_z<1><<<B_, 256, 0, stream>>>(zparts, bybx, lnz_g, lnz_b,
                                        zh + (size_t)k * B_ * D_, zbx_bf,
                                        vh_w1, vh_b1, vh_w2, vh_b2, outp);
    }
  }
}